// Round 3
// baseline (144.398 us; speedup 1.0000x reference)
//
#include <hip/hip_runtime.h>

// Shapes: J=64 inputs, T=64 terms, NV=4 vars, K=8 coeffs, I=64 nodes.
// under/over: [I, 2*J*T+1, NV, K] fp32 ; degrees: [I, NV] each.
namespace {
constexpr int Jc = 64, Tc = 64, NVc = 4, Ic = 64;
constexpr int F4_TERM  = 8;                        // float4 per term (32 floats)
constexpr int TERMS    = 2 * Jc * Tc + 1;          // 8193 terms per node
constexpr int NODE_F4  = TERMS * F4_TERM;          // 65544 float4 per node
constexpr int TILE_F4  = Tc * F4_TERM;             // 512 float4 per input-j tile (8 KB)
constexpr long long SIDE_F4 = (long long)Ic * NODE_F4;   // under size in f4
constexpr long long DEG_BASE_FLT = 2LL * SIDE_F4 * 4;    // 33,558,528 floats
constexpr int SPANS   = 16;                        // contiguous spans per node
constexpr int SPAN_F4 = (2 * Tc * Jc / SPANS) * F4_TERM; // 4096 f4 = 64 KB span
constexpr int MAIN_BLOCKS = 2 * Ic * SPANS;        // 2 sides * 64 nodes * 16 spans = 2048
}

typedef float v4f __attribute__((ext_vector_type(4)));

__device__ __forceinline__ void store4(float4* p, float x, float y, float z, float w) {
    v4f v = {x, y, z, w};
    *reinterpret_cast<v4f*>(p) = v;
}

// Round 3 change: invert decomposition so each block writes ONE contiguous
// 64 KB span (8 input tiles -> 1 output span) instead of 8 chunks scattered
// at ~1 MB stride. Round 2 falsified the nt-store theory (cached == nt ==
// ~2.2 TB/s); write-address topology is the remaining variable vs the 6.5 TB/s
// contiguous fill. Bytes written / instruction counts unchanged; input reads
// grow to 134 MB but are L2-resident (4 MB working set).
__global__ __launch_bounds__(256) void layer_kernel(
    const float4* __restrict__ liu,   // layer_inputs_under  [J,T,NV,K]
    const float4* __restrict__ lio,   // layer_inputs_over   [J,T,NV,K]
    const float*  __restrict__ ud,    // under degrees [J,NV]
    const float*  __restrict__ od,    // over degrees  [J,NV]
    const float*  __restrict__ w,     // weights [I,J]
    const float*  __restrict__ bias,  // biases [I]
    float*        __restrict__ outf)  // under || over || under_deg || over_deg
{
    float4* out = reinterpret_cast<float4*>(outf);
    const int b   = blockIdx.x;
    const int tid = (int)threadIdx.x;

    if (b < MAIN_BLOCKS) {
        // Block = (side s, node i, span p). Span p covers global tiles
        // jj = p*8 .. p*8+7 (jj<64: lio half, jj>=64: liu half).
        const int p = b & (SPANS - 1);
        const int i = (b >> 4) & 63;
        const int s = b >> 10;

        // Per-tile source pointer and scale (all block-uniform -> scalar).
        // under: lio*wn | liu*wp ; over: lio*wp | liu*wn  -> wn iff half==side
        float sv[8];
        const float4* srcs[8];
        #pragma unroll
        for (int ts = 0; ts < 8; ++ts) {
            const int jj = p * 8 + ts;
            const int h  = jj >> 6;
            const int j  = jj & 63;
            const float wv = w[i * Jc + j];
            const float wp = fmaxf(wv, 0.0f);   // relu(w)
            const float wn = fminf(wv, 0.0f);   // -relu(-w)
            sv[ts]   = (h == s) ? wn : wp;
            srcs[ts] = (h ? liu : lio) + j * TILE_F4;
        }

        // var-0 coefficient row = float4 slots 0,1 of each 8-slot term.
        // f = r*256+tid, and 256 % 8 == 0, so (f&7) == (tid&7).
        const bool isv0 = (tid & 7) < 2;

        float4* dst = out + (long long)s * SIDE_F4 + (long long)i * NODE_F4
                          + p * SPAN_F4;
        #pragma unroll
        for (int r = 0; r < 16; ++r) {
            const int f  = r * 256 + tid;       // f4 index within span [0,4096)
            const int ts = r >> 1;              // 512 f4 per tile
            const float4 v = srcs[ts][f & 511];
            const float sc = isv0 ? sv[ts] : 1.0f;
            store4(dst + f, v.x * sc, v.y * sc, v.z * sc, v.w * sc);
        }
    } else {
        // Tail block: bias/ones term (term 8192) for all 128 (side,node) regions + degrees.
        #pragma unroll
        for (int r = 0; r < 4; ++r) {
            const int t    = r * 256 + tid;       // [0,1024) = 128 regions * 8 f4
            const int reg  = t >> 3;
            const int i    = reg >> 1;
            const int s    = reg & 1;
            const int sub  = t & 7;               // f4 slot; var = sub>>1
            const float val = (sub < 2) ? bias[i] : 1.0f;   // var0 row = bias, rest = 1
            const long long off = (long long)s * SIDE_F4 + (long long)i * NODE_F4
                                  + (long long)(2 * Jc * Tc) * F4_TERM + sub;
            store4(out + off, val, val, val, val);
        }
        // degrees: deg[var] = max_j max(ud[j,var], od[j,var]), lane-parallel + shuffle.
        const int lane = tid & 63;                // lane = j
        float m[NVc];
        #pragma unroll
        for (int v = 0; v < NVc; ++v)
            m[v] = fmaxf(ud[lane * NVc + v], od[lane * NVc + v]);
        #pragma unroll
        for (int mask = 1; mask < 64; mask <<= 1) {
            #pragma unroll
            for (int v = 0; v < NVc; ++v)
                m[v] = fmaxf(m[v], __shfl_xor(m[v], mask, 64));
        }
        const float dv = m[tid & 3];              // tid = i*4+var
        outf[DEG_BASE_FLT + tid] = dv;            // under_deg
        outf[DEG_BASE_FLT + 256 + tid] = dv;      // over_deg
    }
}

extern "C" void kernel_launch(void* const* d_in, const int* in_sizes, int n_in,
                              void* d_out, int out_size, void* d_ws, size_t ws_size,
                              hipStream_t stream) {
    const float4* liu  = (const float4*)d_in[0];
    const float4* lio  = (const float4*)d_in[1];
    const float*  ud   = (const float*)d_in[2];
    const float*  od   = (const float*)d_in[3];
    const float*  w    = (const float*)d_in[4];
    const float*  bias = (const float*)d_in[5];
    float* outf = (float*)d_out;

    layer_kernel<<<dim3(MAIN_BLOCKS + 1), dim3(256), 0, stream>>>(
        liu, lio, ud, od, w, bias, outf);
}